// Round 9
// baseline (314.676 us; speedup 1.0000x reference)
//
#include <hip/hip_runtime.h>
#include <hip/hip_fp16.h>
#include <math.h>

#define N_NODES 100000
#define N_EDGES 1600000
#define N_GRAPHS 64
#define EMB 128
#define HID 64

#define BUCKET_BITS 9
#define BUCKET_SZ   512
#define NB          196   // ceil(N_NODES / 512)
#define EPB         4096  // edges per block in bucket passes
#define P12_BLOCKS  391   // ceil(N_EDGES / 4096)
#define NPB         16    // nodes per gin block

// ---------------- fp16 packed helpers ----------------

typedef _Float16 half2_t __attribute__((ext_vector_type(2)));

__device__ inline unsigned hadd2u(unsigned a, unsigned b) {
    __half2 ha = __builtin_bit_cast(__half2, a);
    __half2 hb = __builtin_bit_cast(__half2, b);
    return __builtin_bit_cast(unsigned, __hadd2(ha, hb));
}

__device__ inline unsigned relu2(unsigned v) {
    unsigned m = (v >> 15) & 0x00010001u;
    return v & ~(m * 0xFFFFu);
}

__device__ inline float fdot2h(unsigned a, unsigned b, float c) {
#if __has_builtin(__builtin_amdgcn_fdot2)
    half2_t ha = __builtin_bit_cast(half2_t, a);
    half2_t hb = __builtin_bit_cast(half2_t, b);
    return __builtin_amdgcn_fdot2(ha, hb, c, false);
#else
    __half2 ha = __builtin_bit_cast(__half2, a);
    __half2 hb = __builtin_bit_cast(__half2, b);
    float2 fa = __half22float2(ha);
    float2 fb = __half22float2(hb);
    return fmaf(fa.x, fb.x, fmaf(fa.y, fb.y, c));
#endif
}

__device__ inline unsigned pack2(float a, float b) {
    __half2 p = __floats2half2_rn(a, b);
    return __builtin_bit_cast(unsigned, p);
}

// ---------------- block-wide exclusive scan over 256 threads ----------------

__device__ inline int block_scan_excl_256(int v) {
    int t = threadIdx.x;
    int lane = t & 63, wid = t >> 6;
    int incl = v;
    #pragma unroll
    for (int off = 1; off < 64; off <<= 1) {
        int u = __shfl_up(incl, off);
        if (lane >= off) incl += u;
    }
    __shared__ int wsum[4];
    if (lane == 63) wsum[wid] = incl;
    __syncthreads();
    int woff = 0;
    for (int w = 0; w < wid; ++w) woff += wsum[w];
    __syncthreads();
    return woff + incl - v;
}

// ---------------- CSR build via bucket semi-sort (uint32-packed entries) ----------------
// entry = (dstLocal9 << 17) | src17

__global__ __launch_bounds__(256) void bucket_count(const int* __restrict__ dst,
                                                    int* __restrict__ bucketCnt,
                                                    int* __restrict__ blockBins, int e) {
    __shared__ int bins[NB];
    for (int i = threadIdx.x; i < NB; i += 256) bins[i] = 0;
    __syncthreads();
    int base = blockIdx.x * EPB;
    #pragma unroll
    for (int j = 0; j < 16; ++j) {
        int i = base + j * 256 + threadIdx.x;
        if (i < e) atomicAdd(&bins[dst[i] >> BUCKET_BITS], 1);
    }
    __syncthreads();
    for (int i = threadIdx.x; i < NB; i += 256) {
        int b = bins[i];
        blockBins[blockIdx.x * NB + i] = b;
        if (b) atomicAdd(&bucketCnt[i], b);
    }
}

__global__ void bucket_scan(const int* __restrict__ bucketCnt, int* __restrict__ bucketOff,
                            int* __restrict__ bucketCur, int* __restrict__ row_ptr) {
    int t = threadIdx.x;
    int v = (t < NB) ? bucketCnt[t] : 0;
    int excl = block_scan_excl_256(v);
    if (t < NB) { bucketOff[t] = excl; bucketCur[t] = excl; }
    if (t == 0) { bucketOff[NB] = N_EDGES; row_ptr[N_NODES] = N_EDGES; }
}

__global__ __launch_bounds__(256) void bucket_scatter(const int* __restrict__ src,
                                                      const int* __restrict__ dst,
                                                      const int* __restrict__ blockBins,
                                                      int* __restrict__ bucketCur,
                                                      unsigned* __restrict__ sorted, int e) {
    __shared__ int lbase[NB];
    __shared__ int gbase[NB];
    __shared__ int cur[NB];
    __shared__ unsigned stage[EPB];        // 16 KB
    __shared__ unsigned char stageb[EPB];  // 4 KB: bucket id per staged entry

    int t = threadIdx.x;
    int v = (t < NB) ? blockBins[blockIdx.x * NB + t] : 0;
    int excl = block_scan_excl_256(v);
    if (t < NB) {
        lbase[t] = excl;
        cur[t]   = excl;
        gbase[t] = v ? atomicAdd(&bucketCur[t], v) : 0;
    }
    __syncthreads();

    int base = blockIdx.x * EPB;
    #pragma unroll
    for (int j = 0; j < 16; ++j) {
        int i = base + j * 256 + threadIdx.x;
        if (i < e) {
            int d = dst[i], s = src[i];
            int b = d >> BUCKET_BITS;
            int p = atomicAdd(&cur[b], 1);
            stage[p]  = ((unsigned)(d & (BUCKET_SZ - 1)) << 17) | (unsigned)s;
            stageb[p] = (unsigned char)b;
        }
    }
    __syncthreads();

    int cnt = min(EPB, e - base);
    for (int idx = threadIdx.x; idx < cnt; idx += 256) {
        int b = stageb[idx];
        sorted[gbase[b] + (idx - lbase[b])] = stage[idx];   // contiguous runs per bucket
    }
}

__global__ __launch_bounds__(256) void bucket_csr(const unsigned* __restrict__ sorted,
                                                  const int* __restrict__ bucketOff,
                                                  int* __restrict__ row_ptr,
                                                  int* __restrict__ col_idx) {
    int b  = blockIdx.x;
    int S  = bucketOff[b];
    int Eb = bucketOff[b + 1];
    int n0 = b << BUCKET_BITS;
    int nNodes = min(BUCKET_SZ, N_NODES - n0);

    __shared__ int cnt[BUCKET_SZ];
    __shared__ int excl[BUCKET_SZ];
    __shared__ int cur[BUCKET_SZ];

    for (int i = threadIdx.x; i < BUCKET_SZ; i += 256) cnt[i] = 0;
    __syncthreads();

    for (int idx = S + threadIdx.x; idx < Eb; idx += 256)
        atomicAdd(&cnt[sorted[idx] >> 17], 1);
    __syncthreads();

    int t = threadIdx.x;
    int v = cnt[2 * t] + cnt[2 * t + 1];
    int pe = block_scan_excl_256(v);
    excl[2 * t]     = pe;
    excl[2 * t + 1] = pe + cnt[2 * t];
    __syncthreads();

    for (int i = threadIdx.x; i < nNodes; i += 256)
        row_ptr[n0 + i] = S + excl[i];
    for (int i = threadIdx.x; i < BUCKET_SZ; i += 256) cur[i] = excl[i];
    __syncthreads();

    for (int idx = S + threadIdx.x; idx < Eb; idx += 256) {
        unsigned ed = sorted[idx];
        int ln = (int)(ed >> 17);
        int slot = S + atomicAdd(&cur[ln], 1);
        col_idx[slot] = (int)(ed & 0x1FFFFu);
    }
}

// ---------------- weight pre-pack: 3 x (64x64 fp32) -> packed fp16 [k2][o] ----------------

__global__ void wpack3(const float* __restrict__ w0, const float* __restrict__ w1,
                       const float* __restrict__ w2, unsigned* __restrict__ out) {
    int m = blockIdx.x >> 3;
    int i = (blockIdx.x & 7) * 256 + threadIdx.x;
    const float* W = (m == 0) ? w0 : (m == 1) ? w1 : w2;
    int k2 = i >> 6, o = i & 63;
    out[m * 2048 + i] = pack2(W[(2 * k2) * 64 + o], W[(2 * k2 + 1) * 64 + o]);
}

// ---------------- dense projection: y = h @ W (Din -> 64), fp16 out ----------------

template <int DIN>
__global__ __launch_bounds__(256) void project_kernel(const float* __restrict__ h,
                                                      const float* __restrict__ W,
                                                      ushort* __restrict__ y) {
    int wid  = threadIdx.x >> 6;
    int lane = threadIdx.x & 63;
    int node = blockIdx.x * 64 + lane;
    bool valid = node < N_NODES;
    const float4* row = reinterpret_cast<const float4*>(h + (size_t)(valid ? node : 0) * DIN);
    int ob = __builtin_amdgcn_readfirstlane(wid * 16);

    float acc[16];
    #pragma unroll
    for (int o = 0; o < 16; ++o) acc[o] = 0.0f;

    #pragma unroll 4
    for (int k4 = 0; k4 < DIN / 4; ++k4) {
        float4 a = row[k4];
        #pragma unroll
        for (int kk = 0; kk < 4; ++kk) {
            int k = k4 * 4 + kk;
            float av = (kk == 0) ? a.x : (kk == 1) ? a.y : (kk == 2) ? a.z : a.w;
            const float* wr = W + k * 64 + ob;   // uniform address -> s_load
            #pragma unroll
            for (int o = 0; o < 16; ++o)
                acc[o] = fmaf(av, wr[o], acc[o]);
        }
    }

    if (valid) {
        uint4 p0, p1;
        p0.x = pack2(acc[0], acc[1]);   p0.y = pack2(acc[2], acc[3]);
        p0.z = pack2(acc[4], acc[5]);   p0.w = pack2(acc[6], acc[7]);
        p1.x = pack2(acc[8], acc[9]);   p1.y = pack2(acc[10], acc[11]);
        p1.z = pack2(acc[12], acc[13]); p1.w = pack2(acc[14], acc[15]);
        uint4* yr = reinterpret_cast<uint4*>(y + (size_t)node * 64 + ob);
        yr[0] = p0;
        yr[1] = p1;
    }
}

// ---------------- fused layer: pipelined gather + bias + relu + dot2-GEMM2 ----------------
// Round-7 layout (16 lanes x uint2 per row, 4 rows/load-instr) + minimal pipeline:
// edge ids preloaded to LDS; node t+1's 8 row-loads (32 edges) issued before
// node t's reduce/GEMM2. Tail loop catches deg>32 / id-preload overflow.
// MODE 0: h = relu(out) fp32.  MODE 1: h = out fp16 (for pooling).

template <int MODE>
__global__ __launch_bounds__(256) void gin_layer(const ushort* __restrict__ y,
                                                 const int* __restrict__ row_ptr,
                                                 const int* __restrict__ col_idx,
                                                 const float* __restrict__ b1,
                                                 const unsigned* __restrict__ W2p,
                                                 const float* __restrict__ b2,
                                                 float* __restrict__ hout,
                                                 ushort* __restrict__ hout16) {
    __shared__ unsigned sW2p[32 * 64];   // 8 KB
    __shared__ unsigned stp[4][32];
    __shared__ int sciv[4][128];         // 2 KB: per-wave edge ids

    {
        const uint4* a = reinterpret_cast<const uint4*>(W2p);
        uint4* dd = reinterpret_cast<uint4*>(sW2p);
        dd[threadIdx.x]       = a[threadIdx.x];
        dd[threadIdx.x + 256] = a[threadIdx.x + 256];
    }
    __syncthreads();

    int wid = threadIdx.x >> 6, lane = threadIdx.x & 63;
    int e4 = lane >> 4, c16 = lane & 15;
    int nb4 = blockIdx.x * NPB + wid * 4;

    const uint2* yp = reinterpret_cast<const uint2*>(y);   // row = 16 uint2
    int* civ = sciv[wid];

    int rpl  = row_ptr[nb4 + min(lane, 4)];
    int s0   = __shfl(rpl, 0);
    int eAll = __shfl(rpl, 4);

    civ[lane]      = (s0 + lane < eAll)      ? col_idx[s0 + lane]      : 0;
    civ[64 + lane] = (s0 + 64 + lane < eAll) ? col_idx[s0 + 64 + lane] : 0;
    // same-wave LDS dep: compiler inserts lgkmcnt waits; no barrier needed.

    float4 b1f = reinterpret_cast<const float4*>(b1)[c16];
    unsigned bp0 = pack2(b1f.x, b1f.y), bp1 = pack2(b1f.z, b1f.w);
    float b2v = b2[lane];

    uint2 A[8], B[8], AS, BS;

#define PREFETCH(T, U, US_)                                                        \
    {                                                                              \
        int st_ = __shfl(rpl, T), en_ = __shfl(rpl, (T) + 1);                      \
        int pe_ = min(min(en_, st_ + 32), s0 + 128);                               \
        int d_  = st_ - s0 + e4;                                                   \
        int p_  = st_ + e4;                                                        \
        uint2 z_ = make_uint2(0u, 0u);                                             \
        US_ = z_;                                                                  \
        if (e4 == 0) US_ = yp[(size_t)(nb4 + (T)) * 16 + c16];                     \
        _Pragma("unroll")                                                          \
        for (int j = 0; j < 8; ++j)                                                \
            U[j] = (p_ + 4 * j < pe_) ? yp[(size_t)civ[d_ + 4 * j] * 16 + c16]     \
                                      : z_;                                        \
    }

    PREFETCH(0, A, AS)

#define GIN_ITER(T, CU, CS, NU, NS)                                                \
    {                                                                              \
        int st = __shfl(rpl, T), en = __shfl(rpl, (T) + 1);                        \
        int node = nb4 + (T);                                                      \
        if ((T) < 3) PREFETCH((T) + 1, NU, NS)                                     \
        unsigned a0 = CS.x, a1 = CS.y;                                             \
        _Pragma("unroll")                                                          \
        for (int j = 0; j < 8; ++j) {                                              \
            a0 = hadd2u(a0, CU[j].x);                                              \
            a1 = hadd2u(a1, CU[j].y);                                              \
        }                                                                          \
        int pe = min(min(en, st + 32), s0 + 128);                                  \
        for (int base = pe; base < en; base += 4) {    /* rare */                  \
            uint2 v = make_uint2(0u, 0u);                                          \
            int p2 = base + e4;                                                    \
            if (p2 < en) v = yp[(size_t)col_idx[p2] * 16 + c16];                   \
            a0 = hadd2u(a0, v.x); a1 = hadd2u(a1, v.y);                            \
        }                                                                          \
        a0 = hadd2u(a0, (unsigned)__shfl_xor((int)a0, 16));                        \
        a1 = hadd2u(a1, (unsigned)__shfl_xor((int)a1, 16));                        \
        a0 = hadd2u(a0, (unsigned)__shfl_xor((int)a0, 32));                        \
        a1 = hadd2u(a1, (unsigned)__shfl_xor((int)a1, 32));                        \
        a0 = relu2(hadd2u(a0, bp0));                                               \
        a1 = relu2(hadd2u(a1, bp1));                                               \
        if (e4 == 0)                                                               \
            reinterpret_cast<uint2*>(stp[wid])[c16] = make_uint2(a0, a1);          \
        float uacc = b2v;                                                          \
        const uint4* sp = reinterpret_cast<const uint4*>(stp[wid]);                \
        _Pragma("unroll")                                                          \
        for (int j = 0; j < 8; ++j) {                                              \
            uint4 q = sp[j];                                                       \
            uacc = fdot2h(q.x, sW2p[(4 * j + 0) * 64 + lane], uacc);               \
            uacc = fdot2h(q.y, sW2p[(4 * j + 1) * 64 + lane], uacc);               \
            uacc = fdot2h(q.z, sW2p[(4 * j + 2) * 64 + lane], uacc);               \
            uacc = fdot2h(q.w, sW2p[(4 * j + 3) * 64 + lane], uacc);               \
        }                                                                          \
        if (MODE == 0) {                                                           \
            hout[(size_t)node * 64 + lane] = fmaxf(uacc, 0.0f);                    \
        } else {                                                                   \
            hout16[(size_t)node * 64 + lane] =                                     \
                __half_as_ushort(__float2half_rn(uacc));                           \
        }                                                                          \
    }

    GIN_ITER(0, A, AS, B, BS)
    GIN_ITER(1, B, BS, A, AS)
    GIN_ITER(2, A, AS, B, BS)
    GIN_ITER(3, B, BS, A, AS)
#undef GIN_ITER
#undef PREFETCH
}

// ---------------- pooling: segment mean over fp16 h (batch is sorted) ----------------

__global__ __launch_bounds__(256) void pool_kernel(const ushort* __restrict__ h,
                                                   const int* __restrict__ batch,
                                                   float* __restrict__ pool,
                                                   float* __restrict__ counts, int n) {
    int gwave = (blockIdx.x * 256 + threadIdx.x) >> 6;
    int lane  = threadIdx.x & 63;
    int s = gwave * 64;
    if (s >= n) return;
    int nhere = min(64, n - s);

    int bv = (s + lane < n) ? batch[s + lane] : -1;
    int cur = __shfl(bv, 0);
    float acc = 0.0f, cnt = 0.0f;

    #pragma unroll 1
    for (int i0 = 0; i0 < 64; i0 += 8) {
        float v[8];
        #pragma unroll
        for (int j = 0; j < 8; ++j) {
            int i = i0 + j;
            v[j] = (i < nhere)
                 ? __half2float(__ushort_as_half(h[(size_t)(s + i) * 64 + lane]))
                 : 0.0f;
        }
        #pragma unroll
        for (int j = 0; j < 8; ++j) {
            int i = i0 + j;
            if (i < nhere) {
                int g = __shfl(bv, i);
                if (g != cur) {   // wave-uniform, rare
                    atomicAdd(&pool[cur * 64 + lane], acc);
                    if (lane == 0) atomicAdd(&counts[cur], cnt);
                    cur = g; acc = 0.0f; cnt = 0.0f;
                }
                acc += v[j];
                cnt += 1.0f;
            }
        }
    }
    atomicAdd(&pool[cur * 64 + lane], acc);
    if (lane == 0) atomicAdd(&counts[cur], cnt);
}

// ---------------- head: pooled @ fc1 + b, @ pred + b, sigmoid ----------------

__global__ void head_kernel(const float* __restrict__ pool, const float* __restrict__ counts,
                            const float* __restrict__ fc1_W, const float* __restrict__ fc1_b,
                            const float* __restrict__ pred_W, const float* __restrict__ pred_b,
                            float* __restrict__ out) {
    int g = blockIdx.x;
    int t = threadIdx.x;
    float s = 0.0f;
    if (t < 32) {
        float cnt = fmaxf(counts[g], 1.0f);
        float inv = 1.0f / cnt;
        float f = fc1_b[t];
        #pragma unroll
        for (int k = 0; k < 64; ++k)
            f = fmaf(pool[g * 64 + k] * inv, fc1_W[k * 32 + t], f);
        s = f * pred_W[t];
    }
    #pragma unroll
    for (int off = 32; off > 0; off >>= 1) s += __shfl_down(s, off);
    if (t == 0) out[g] = 1.0f / (1.0f + expf(-(s + pred_b[0])));
}

// ---------------- launch ----------------

extern "C" void kernel_launch(void* const* d_in, const int* in_sizes, int n_in,
                              void* d_out, int out_size, void* d_ws, size_t ws_size,
                              hipStream_t stream) {
    const float* x      = (const float*)d_in[0];
    const int*   e_src  = (const int*)d_in[1];
    const int*   e_dst  = ((const int*)d_in[1]) + N_EDGES;
    const int*   batch  = (const int*)d_in[2];
    const float* c1_W1 = (const float*)d_in[3];
    const float* c1_b1 = (const float*)d_in[4];
    const float* c1_W2 = (const float*)d_in[5];
    const float* c1_b2 = (const float*)d_in[6];
    const float* c2_W1 = (const float*)d_in[7];
    const float* c2_b1 = (const float*)d_in[8];
    const float* c2_W2 = (const float*)d_in[9];
    const float* c2_b2 = (const float*)d_in[10];
    const float* c3_W1 = (const float*)d_in[11];
    const float* c3_b1 = (const float*)d_in[12];
    const float* c3_W2 = (const float*)d_in[13];
    const float* c3_b2 = (const float*)d_in[14];
    const float* fc1_W = (const float*)d_in[15];
    const float* fc1_b = (const float*)d_in[16];
    const float* predW = (const float*)d_in[17];
    const float* predb = (const float*)d_in[18];
    float* out = (float*)d_out;

    char* ws = (char*)d_ws;
    size_t off = 0;
    auto carve = [&](size_t bytes) {
        char* p = ws + off;
        off += (bytes + 255) & ~(size_t)255;
        return p;
    };
    ushort* y        = (ushort*)carve((size_t)N_NODES * 64 * 2);  // 12.8 MB
    float*  h        = (float*)carve((size_t)N_NODES * 64 * 4);   // 25.6 MB
    int*    row_ptr  = (int*)carve(((size_t)N_NODES + 1) * 4);
    int*    col_idx  = (int*)carve((size_t)N_EDGES * 4);
    int*    bucketCnt = (int*)carve(NB * 4);
    int*    bucketOff = (int*)carve((NB + 1) * 4);
    int*    bucketCur = (int*)carve(NB * 4);
    int*    blockBins = (int*)carve((size_t)P12_BLOCKS * NB * 4); // 306 KB
    float*  pool     = (float*)carve(N_GRAPHS * 64 * 4);
    float*  counts   = (float*)carve(N_GRAPHS * 4);
    unsigned* Wp     = (unsigned*)carve(3 * 2048 * 4);
    unsigned* sorted = (unsigned*)y;        // 6.4 MB, dead before proj1 writes y
    ushort* hbuf     = (ushort*)h;          // layer-3 fp16 out, h dead by then
    (void)ws_size; (void)n_in; (void)in_sizes; (void)out_size;

    const int GIN_BLOCKS  = N_NODES / NPB;             // 6250
    const int PROJ_BLOCKS = (N_NODES + 63) / 64;       // 1563
    const int POOL_BLOCKS = (N_NODES + 255) / 256;     // 391

    hipMemsetAsync(bucketCnt, 0, NB * 4, stream);
    hipMemsetAsync(pool, 0, (N_GRAPHS * 64 + N_GRAPHS) * 4 + 256, stream);

    wpack3<<<24, 256, 0, stream>>>(c1_W2, c2_W2, c3_W2, Wp);

    // CSR build via bucket semi-sort
    bucket_count<<<P12_BLOCKS, 256, 0, stream>>>(e_dst, bucketCnt, blockBins, N_EDGES);
    bucket_scan<<<1, 256, 0, stream>>>(bucketCnt, bucketOff, bucketCur, row_ptr);
    bucket_scatter<<<P12_BLOCKS, 256, 0, stream>>>(e_src, e_dst, blockBins, bucketCur,
                                                   sorted, N_EDGES);
    bucket_csr<<<NB, 256, 0, stream>>>(sorted, bucketOff, row_ptr, col_idx);

    // layer 1 (project 128->64 BEFORE aggregation: linearity of W1)
    project_kernel<EMB><<<PROJ_BLOCKS, 256, 0, stream>>>(x, c1_W1, y);
    gin_layer<0><<<GIN_BLOCKS, 256, 0, stream>>>(y, row_ptr, col_idx, c1_b1,
                                                 Wp + 0 * 2048, c1_b2, h, nullptr);
    // layer 2
    project_kernel<HID><<<PROJ_BLOCKS, 256, 0, stream>>>(h, c2_W1, y);
    gin_layer<0><<<GIN_BLOCKS, 256, 0, stream>>>(y, row_ptr, col_idx, c2_b1,
                                                 Wp + 1 * 2048, c2_b2, h, nullptr);
    // layer 3 (no output relu, fp16 out for pooling)
    project_kernel<HID><<<PROJ_BLOCKS, 256, 0, stream>>>(h, c3_W1, y);
    gin_layer<1><<<GIN_BLOCKS, 256, 0, stream>>>(y, row_ptr, col_idx, c3_b1,
                                                 Wp + 2 * 2048, c3_b2, nullptr, hbuf);

    // pool + head
    pool_kernel<<<POOL_BLOCKS, 256, 0, stream>>>(hbuf, batch, pool, counts, N_NODES);
    head_kernel<<<N_GRAPHS, 64, 0, stream>>>(pool, counts, fc1_W, fc1_b, predW, predb, out);
}

// Round 10
// 303.040 us; speedup vs baseline: 1.0384x; 1.0384x over previous
//
#include <hip/hip_runtime.h>
#include <hip/hip_fp16.h>
#include <math.h>

#define N_NODES 100000
#define N_EDGES 1600000
#define N_GRAPHS 64
#define EMB 128
#define HID 64

#define BUCKET_BITS 9
#define BUCKET_SZ   512
#define NB          196   // ceil(N_NODES / 512)
#define EPB         4096  // edges per block in bucket passes
#define P12_BLOCKS  391   // ceil(N_EDGES / 4096)
#define NPB         16    // nodes per gin block

// ---------------- fp16 packed helpers ----------------

typedef _Float16 half2_t __attribute__((ext_vector_type(2)));

__device__ inline unsigned hadd2u(unsigned a, unsigned b) {
    __half2 ha = __builtin_bit_cast(__half2, a);
    __half2 hb = __builtin_bit_cast(__half2, b);
    return __builtin_bit_cast(unsigned, __hadd2(ha, hb));
}

__device__ inline unsigned relu2(unsigned v) {
    unsigned m = (v >> 15) & 0x00010001u;
    return v & ~(m * 0xFFFFu);
}

__device__ inline float fdot2h(unsigned a, unsigned b, float c) {
#if __has_builtin(__builtin_amdgcn_fdot2)
    half2_t ha = __builtin_bit_cast(half2_t, a);
    half2_t hb = __builtin_bit_cast(half2_t, b);
    return __builtin_amdgcn_fdot2(ha, hb, c, false);
#else
    __half2 ha = __builtin_bit_cast(__half2, a);
    __half2 hb = __builtin_bit_cast(__half2, b);
    float2 fa = __half22float2(ha);
    float2 fb = __half22float2(hb);
    return fmaf(fa.x, fb.x, fmaf(fa.y, fb.y, c));
#endif
}

__device__ inline unsigned pack2(float a, float b) {
    __half2 p = __floats2half2_rn(a, b);
    return __builtin_bit_cast(unsigned, p);
}

// ---------------- block-wide exclusive scan over 256 threads ----------------

__device__ inline int block_scan_excl_256(int v) {
    int t = threadIdx.x;
    int lane = t & 63, wid = t >> 6;
    int incl = v;
    #pragma unroll
    for (int off = 1; off < 64; off <<= 1) {
        int u = __shfl_up(incl, off);
        if (lane >= off) incl += u;
    }
    __shared__ int wsum[4];
    if (lane == 63) wsum[wid] = incl;
    __syncthreads();
    int woff = 0;
    for (int w = 0; w < wid; ++w) woff += wsum[w];
    __syncthreads();
    return woff + incl - v;
}

// ---------------- CSR build via bucket semi-sort (uint32-packed entries) ----------------
// entry = (dstLocal9 << 17) | src17

__global__ __launch_bounds__(256) void bucket_count(const int* __restrict__ dst,
                                                    int* __restrict__ bucketCnt,
                                                    int* __restrict__ blockBins, int e) {
    __shared__ int bins[NB];
    for (int i = threadIdx.x; i < NB; i += 256) bins[i] = 0;
    __syncthreads();
    int base = blockIdx.x * EPB;
    #pragma unroll
    for (int j = 0; j < 16; ++j) {
        int i = base + j * 256 + threadIdx.x;
        if (i < e) atomicAdd(&bins[dst[i] >> BUCKET_BITS], 1);
    }
    __syncthreads();
    for (int i = threadIdx.x; i < NB; i += 256) {
        int b = bins[i];
        blockBins[blockIdx.x * NB + i] = b;
        if (b) atomicAdd(&bucketCnt[i], b);
    }
}

__global__ void bucket_scan(const int* __restrict__ bucketCnt, int* __restrict__ bucketOff,
                            int* __restrict__ bucketCur, int* __restrict__ row_ptr) {
    int t = threadIdx.x;
    int v = (t < NB) ? bucketCnt[t] : 0;
    int excl = block_scan_excl_256(v);
    if (t < NB) { bucketOff[t] = excl; bucketCur[t] = excl; }
    if (t == 0) { bucketOff[NB] = N_EDGES; row_ptr[N_NODES] = N_EDGES; }
}

__global__ __launch_bounds__(256) void bucket_scatter(const int* __restrict__ src,
                                                      const int* __restrict__ dst,
                                                      const int* __restrict__ blockBins,
                                                      int* __restrict__ bucketCur,
                                                      unsigned* __restrict__ sorted, int e) {
    __shared__ int lbase[NB];
    __shared__ int gbase[NB];
    __shared__ int cur[NB];
    __shared__ unsigned stage[EPB];        // 16 KB
    __shared__ unsigned char stageb[EPB];  // 4 KB

    int t = threadIdx.x;
    int v = (t < NB) ? blockBins[blockIdx.x * NB + t] : 0;
    int excl = block_scan_excl_256(v);
    if (t < NB) {
        lbase[t] = excl;
        cur[t]   = excl;
        gbase[t] = v ? atomicAdd(&bucketCur[t], v) : 0;
    }
    __syncthreads();

    int base = blockIdx.x * EPB;
    #pragma unroll
    for (int j = 0; j < 16; ++j) {
        int i = base + j * 256 + threadIdx.x;
        if (i < e) {
            int d = dst[i], s = src[i];
            int b = d >> BUCKET_BITS;
            int p = atomicAdd(&cur[b], 1);
            stage[p]  = ((unsigned)(d & (BUCKET_SZ - 1)) << 17) | (unsigned)s;
            stageb[p] = (unsigned char)b;
        }
    }
    __syncthreads();

    int cnt = min(EPB, e - base);
    for (int idx = threadIdx.x; idx < cnt; idx += 256) {
        int b = stageb[idx];
        sorted[gbase[b] + (idx - lbase[b])] = stage[idx];   // contiguous runs per bucket
    }
}

__global__ __launch_bounds__(256) void bucket_csr(const unsigned* __restrict__ sorted,
                                                  const int* __restrict__ bucketOff,
                                                  int* __restrict__ row_ptr,
                                                  int* __restrict__ col_idx) {
    int b  = blockIdx.x;
    int S  = bucketOff[b];
    int Eb = bucketOff[b + 1];
    int n0 = b << BUCKET_BITS;
    int nNodes = min(BUCKET_SZ, N_NODES - n0);

    __shared__ int cnt[BUCKET_SZ];
    __shared__ int excl[BUCKET_SZ];
    __shared__ int cur[BUCKET_SZ];

    for (int i = threadIdx.x; i < BUCKET_SZ; i += 256) cnt[i] = 0;
    __syncthreads();

    for (int idx = S + threadIdx.x; idx < Eb; idx += 256)
        atomicAdd(&cnt[sorted[idx] >> 17], 1);
    __syncthreads();

    int t = threadIdx.x;
    int v = cnt[2 * t] + cnt[2 * t + 1];
    int pe = block_scan_excl_256(v);
    excl[2 * t]     = pe;
    excl[2 * t + 1] = pe + cnt[2 * t];
    __syncthreads();

    for (int i = threadIdx.x; i < nNodes; i += 256)
        row_ptr[n0 + i] = S + excl[i];
    for (int i = threadIdx.x; i < BUCKET_SZ; i += 256) cur[i] = excl[i];
    __syncthreads();

    for (int idx = S + threadIdx.x; idx < Eb; idx += 256) {
        unsigned ed = sorted[idx];
        int ln = (int)(ed >> 17);
        int slot = S + atomicAdd(&cur[ln], 1);
        col_idx[slot] = (int)(ed & 0x1FFFFu);
    }
}

// ---------------- weight pre-pack: 3 x (64x64 fp32) -> packed fp16 [k2][o] ----------------

__global__ void wpack3(const float* __restrict__ w0, const float* __restrict__ w1,
                       const float* __restrict__ w2, unsigned* __restrict__ out) {
    int m = blockIdx.x >> 3;
    int i = (blockIdx.x & 7) * 256 + threadIdx.x;
    const float* W = (m == 0) ? w0 : (m == 1) ? w1 : w2;
    int k2 = i >> 6, o = i & 63;
    out[m * 2048 + i] = pack2(W[(2 * k2) * 64 + o], W[(2 * k2 + 1) * 64 + o]);
}

// ---------------- dense projection: y = h @ W (Din -> 64), fp16 out ----------------

template <int DIN>
__global__ __launch_bounds__(256) void project_kernel(const float* __restrict__ h,
                                                      const float* __restrict__ W,
                                                      ushort* __restrict__ y) {
    int wid  = threadIdx.x >> 6;
    int lane = threadIdx.x & 63;
    int node = blockIdx.x * 64 + lane;
    bool valid = node < N_NODES;
    const float4* row = reinterpret_cast<const float4*>(h + (size_t)(valid ? node : 0) * DIN);
    int ob = __builtin_amdgcn_readfirstlane(wid * 16);

    float acc[16];
    #pragma unroll
    for (int o = 0; o < 16; ++o) acc[o] = 0.0f;

    #pragma unroll 4
    for (int k4 = 0; k4 < DIN / 4; ++k4) {
        float4 a = row[k4];
        #pragma unroll
        for (int kk = 0; kk < 4; ++kk) {
            int k = k4 * 4 + kk;
            float av = (kk == 0) ? a.x : (kk == 1) ? a.y : (kk == 2) ? a.z : a.w;
            const float* wr = W + k * 64 + ob;   // uniform address -> s_load
            #pragma unroll
            for (int o = 0; o < 16; ++o)
                acc[o] = fmaf(av, wr[o], acc[o]);
        }
    }

    if (valid) {
        uint4 p0, p1;
        p0.x = pack2(acc[0], acc[1]);   p0.y = pack2(acc[2], acc[3]);
        p0.z = pack2(acc[4], acc[5]);   p0.w = pack2(acc[6], acc[7]);
        p1.x = pack2(acc[8], acc[9]);   p1.y = pack2(acc[10], acc[11]);
        p1.z = pack2(acc[12], acc[13]); p1.w = pack2(acc[14], acc[15]);
        uint4* yr = reinterpret_cast<uint4*>(y + (size_t)node * 64 + ob);
        yr[0] = p0;
        yr[1] = p1;
    }
}

// ---------------- fused layer (round-7 structure, proven 48.5us) ----------------
// lane = (e4 = lane>>4, c16 = lane&15). 16 lanes x uint2 (8B, 4 halves) = one
// 128B fp16 row per group; 4 rows per load instruction, 16 rows in flight.
// Accumulate packed fp16 (v_pk_add_f16); GEMM2 with v_dot2_f32_f16 on fp16 W2.
// 36 VGPR -> 8 waves/SIMD: TLP does the latency hiding (reg pipeline regressed, R9).
// MODE 0: h = relu(out) fp32.  MODE 1: h = out fp16 (for pooling).

template <int MODE>
__global__ __launch_bounds__(256) void gin_layer(const ushort* __restrict__ y,
                                                 const int* __restrict__ row_ptr,
                                                 const int* __restrict__ col_idx,
                                                 const float* __restrict__ b1,
                                                 const unsigned* __restrict__ W2p,
                                                 const float* __restrict__ b2,
                                                 float* __restrict__ hout,
                                                 ushort* __restrict__ hout16) {
    __shared__ unsigned sW2p[32 * 64];   // packed half2 [k2][o], 8 KB
    __shared__ unsigned stp[4][32];      // packed st per wave

    {
        const uint4* a = reinterpret_cast<const uint4*>(W2p);
        uint4* dd = reinterpret_cast<uint4*>(sW2p);
        dd[threadIdx.x]       = a[threadIdx.x];
        dd[threadIdx.x + 256] = a[threadIdx.x + 256];
    }
    __syncthreads();

    int wid  = threadIdx.x >> 6;
    int lane = threadIdx.x & 63;
    int e4   = lane >> 4;       // edge sub-group 0..3
    int c16  = lane & 15;       // channel chunk (4 halves) 0..15

    const uint2* yp = reinterpret_cast<const uint2*>(y);  // row stride = 16 uint2
    float4 b1f = reinterpret_cast<const float4*>(b1)[c16];
    unsigned bp0 = pack2(b1f.x, b1f.y);
    unsigned bp1 = pack2(b1f.z, b1f.w);
    float b2v = b2[lane];

    #pragma unroll 1
    for (int t = 0; t < 4; ++t) {
        int node = blockIdx.x * NPB + wid * 4 + t;

        int start = row_ptr[node];
        int end   = row_ptr[node + 1];

        unsigned a0 = 0u, a1 = 0u;
        if (e4 == 0) {
            uint2 s = yp[(size_t)node * 16 + c16];   // self term
            a0 = s.x; a1 = s.y;
        }

        int base = start;
        // main: 16 edges per iteration, 4 row-loads in flight per lane-group
        for (; base + 16 <= end; base += 16) {
            int i0 = col_idx[base + e4];
            int i1 = col_idx[base + 4 + e4];
            int i2 = col_idx[base + 8 + e4];
            int i3 = col_idx[base + 12 + e4];
            uint2 u0 = yp[(size_t)i0 * 16 + c16];
            uint2 u1 = yp[(size_t)i1 * 16 + c16];
            uint2 u2 = yp[(size_t)i2 * 16 + c16];
            uint2 u3 = yp[(size_t)i3 * 16 + c16];
            a0 = hadd2u(a0, u0.x); a1 = hadd2u(a1, u0.y);
            a0 = hadd2u(a0, u1.x); a1 = hadd2u(a1, u1.y);
            a0 = hadd2u(a0, u2.x); a1 = hadd2u(a1, u2.y);
            a0 = hadd2u(a0, u3.x); a1 = hadd2u(a1, u3.y);
        }
        // tail: rem < 16, straight-line predicated (loads stay in flight)
        {
            uint2 z = make_uint2(0u, 0u);
            uint2 u0 = z, u1 = z, u2 = z, u3 = z;
            if (base + e4 < end)      u0 = yp[(size_t)col_idx[base + e4] * 16 + c16];
            if (base + 4 + e4 < end)  u1 = yp[(size_t)col_idx[base + 4 + e4] * 16 + c16];
            if (base + 8 + e4 < end)  u2 = yp[(size_t)col_idx[base + 8 + e4] * 16 + c16];
            if (base + 12 + e4 < end) u3 = yp[(size_t)col_idx[base + 12 + e4] * 16 + c16];
            a0 = hadd2u(a0, u0.x); a1 = hadd2u(a1, u0.y);
            a0 = hadd2u(a0, u1.x); a1 = hadd2u(a1, u1.y);
            a0 = hadd2u(a0, u2.x); a1 = hadd2u(a1, u2.y);
            a0 = hadd2u(a0, u3.x); a1 = hadd2u(a1, u3.y);
        }

        // reduce across the 4 edge groups (lanes differing in bits 4,5)
        #pragma unroll
        for (int m = 16; m <= 32; m <<= 1) {
            a0 = hadd2u(a0, (unsigned)__shfl_xor((int)a0, m));
            a1 = hadd2u(a1, (unsigned)__shfl_xor((int)a1, m));
        }

        // bias + relu in packed fp16; publish to wave-private st
        a0 = relu2(hadd2u(a0, bp0));
        a1 = relu2(hadd2u(a1, bp1));
        if (e4 == 0)
            reinterpret_cast<uint2*>(stp[wid])[c16] = make_uint2(a0, a1);

        // GEMM2: u[lane] = b2[lane] + sum_k2 dot2(st2[k2], W2p[k2][lane])
        float u = b2v;
        const uint4* sp = reinterpret_cast<const uint4*>(stp[wid]);
        #pragma unroll
        for (int j = 0; j < 8; ++j) {
            uint4 q = sp[j];
            u = fdot2h(q.x, sW2p[(4 * j + 0) * 64 + lane], u);
            u = fdot2h(q.y, sW2p[(4 * j + 1) * 64 + lane], u);
            u = fdot2h(q.z, sW2p[(4 * j + 2) * 64 + lane], u);
            u = fdot2h(q.w, sW2p[(4 * j + 3) * 64 + lane], u);
        }
        if (MODE == 0) {
            hout[(size_t)node * 64 + lane] = fmaxf(u, 0.0f);
        } else {
            hout16[(size_t)node * 64 + lane] = __half_as_ushort(__float2half_rn(u));
        }
    }
}

// ---------------- pooling: segment mean over fp16 h (batch is sorted) ----------------

__global__ __launch_bounds__(256) void pool_kernel(const ushort* __restrict__ h,
                                                   const int* __restrict__ batch,
                                                   float* __restrict__ pool,
                                                   float* __restrict__ counts, int n) {
    int gwave = (blockIdx.x * 256 + threadIdx.x) >> 6;
    int lane  = threadIdx.x & 63;
    int s = gwave * 64;
    if (s >= n) return;
    int nhere = min(64, n - s);

    int bv = (s + lane < n) ? batch[s + lane] : -1;
    int cur = __shfl(bv, 0);
    float acc = 0.0f, cnt = 0.0f;

    #pragma unroll 1
    for (int i0 = 0; i0 < 64; i0 += 8) {
        float v[8];
        #pragma unroll
        for (int j = 0; j < 8; ++j) {
            int i = i0 + j;
            v[j] = (i < nhere)
                 ? __half2float(__ushort_as_half(h[(size_t)(s + i) * 64 + lane]))
                 : 0.0f;
        }
        #pragma unroll
        for (int j = 0; j < 8; ++j) {
            int i = i0 + j;
            if (i < nhere) {
                int g = __shfl(bv, i);
                if (g != cur) {   // wave-uniform, rare
                    atomicAdd(&pool[cur * 64 + lane], acc);
                    if (lane == 0) atomicAdd(&counts[cur], cnt);
                    cur = g; acc = 0.0f; cnt = 0.0f;
                }
                acc += v[j];
                cnt += 1.0f;
            }
        }
    }
    atomicAdd(&pool[cur * 64 + lane], acc);
    if (lane == 0) atomicAdd(&counts[cur], cnt);
}

// ---------------- head: pooled @ fc1 + b, @ pred + b, sigmoid ----------------

__global__ void head_kernel(const float* __restrict__ pool, const float* __restrict__ counts,
                            const float* __restrict__ fc1_W, const float* __restrict__ fc1_b,
                            const float* __restrict__ pred_W, const float* __restrict__ pred_b,
                            float* __restrict__ out) {
    int g = blockIdx.x;
    int t = threadIdx.x;
    float s = 0.0f;
    if (t < 32) {
        float cnt = fmaxf(counts[g], 1.0f);
        float inv = 1.0f / cnt;
        float f = fc1_b[t];
        #pragma unroll
        for (int k = 0; k < 64; ++k)
            f = fmaf(pool[g * 64 + k] * inv, fc1_W[k * 32 + t], f);
        s = f * pred_W[t];
    }
    #pragma unroll
    for (int off = 32; off > 0; off >>= 1) s += __shfl_down(s, off);
    if (t == 0) out[g] = 1.0f / (1.0f + expf(-(s + pred_b[0])));
}

// ---------------- launch ----------------

extern "C" void kernel_launch(void* const* d_in, const int* in_sizes, int n_in,
                              void* d_out, int out_size, void* d_ws, size_t ws_size,
                              hipStream_t stream) {
    const float* x      = (const float*)d_in[0];
    const int*   e_src  = (const int*)d_in[1];
    const int*   e_dst  = ((const int*)d_in[1]) + N_EDGES;
    const int*   batch  = (const int*)d_in[2];
    const float* c1_W1 = (const float*)d_in[3];
    const float* c1_b1 = (const float*)d_in[4];
    const float* c1_W2 = (const float*)d_in[5];
    const float* c1_b2 = (const float*)d_in[6];
    const float* c2_W1 = (const float*)d_in[7];
    const float* c2_b1 = (const float*)d_in[8];
    const float* c2_W2 = (const float*)d_in[9];
    const float* c2_b2 = (const float*)d_in[10];
    const float* c3_W1 = (const float*)d_in[11];
    const float* c3_b1 = (const float*)d_in[12];
    const float* c3_W2 = (const float*)d_in[13];
    const float* c3_b2 = (const float*)d_in[14];
    const float* fc1_W = (const float*)d_in[15];
    const float* fc1_b = (const float*)d_in[16];
    const float* predW = (const float*)d_in[17];
    const float* predb = (const float*)d_in[18];
    float* out = (float*)d_out;

    char* ws = (char*)d_ws;
    size_t off = 0;
    auto carve = [&](size_t bytes) {
        char* p = ws + off;
        off += (bytes + 255) & ~(size_t)255;
        return p;
    };
    ushort* y        = (ushort*)carve((size_t)N_NODES * 64 * 2);  // 12.8 MB
    float*  h        = (float*)carve((size_t)N_NODES * 64 * 4);   // 25.6 MB
    int*    row_ptr  = (int*)carve(((size_t)N_NODES + 1) * 4);
    int*    col_idx  = (int*)carve((size_t)N_EDGES * 4);
    int*    bucketCnt = (int*)carve(NB * 4);
    int*    bucketOff = (int*)carve((NB + 1) * 4);
    int*    bucketCur = (int*)carve(NB * 4);
    int*    blockBins = (int*)carve((size_t)P12_BLOCKS * NB * 4); // 306 KB
    float*  pool     = (float*)carve(N_GRAPHS * 64 * 4);
    float*  counts   = (float*)carve(N_GRAPHS * 4);
    unsigned* Wp     = (unsigned*)carve(3 * 2048 * 4);
    unsigned* sorted = (unsigned*)y;        // 6.4 MB, dead before proj1 writes y
    ushort* hbuf     = (ushort*)h;          // layer-3 fp16 out, h dead by then
    (void)ws_size; (void)n_in; (void)in_sizes; (void)out_size;

    const int GIN_BLOCKS  = N_NODES / NPB;             // 6250
    const int PROJ_BLOCKS = (N_NODES + 63) / 64;       // 1563
    const int POOL_BLOCKS = (N_NODES + 255) / 256;     // 391

    hipMemsetAsync(bucketCnt, 0, NB * 4, stream);
    hipMemsetAsync(pool, 0, (N_GRAPHS * 64 + N_GRAPHS) * 4 + 256, stream);

    wpack3<<<24, 256, 0, stream>>>(c1_W2, c2_W2, c3_W2, Wp);

    // CSR build via bucket semi-sort
    bucket_count<<<P12_BLOCKS, 256, 0, stream>>>(e_dst, bucketCnt, blockBins, N_EDGES);
    bucket_scan<<<1, 256, 0, stream>>>(bucketCnt, bucketOff, bucketCur, row_ptr);
    bucket_scatter<<<P12_BLOCKS, 256, 0, stream>>>(e_src, e_dst, blockBins, bucketCur,
                                                   sorted, N_EDGES);
    bucket_csr<<<NB, 256, 0, stream>>>(sorted, bucketOff, row_ptr, col_idx);

    // layer 1 (project 128->64 BEFORE aggregation: linearity of W1)
    project_kernel<EMB><<<PROJ_BLOCKS, 256, 0, stream>>>(x, c1_W1, y);
    gin_layer<0><<<GIN_BLOCKS, 256, 0, stream>>>(y, row_ptr, col_idx, c1_b1,
                                                 Wp + 0 * 2048, c1_b2, h, nullptr);
    // layer 2
    project_kernel<HID><<<PROJ_BLOCKS, 256, 0, stream>>>(h, c2_W1, y);
    gin_layer<0><<<GIN_BLOCKS, 256, 0, stream>>>(y, row_ptr, col_idx, c2_b1,
                                                 Wp + 1 * 2048, c2_b2, h, nullptr);
    // layer 3 (no output relu, fp16 out for pooling)
    project_kernel<HID><<<GIN_BLOCKS / 4, 256, 0, stream>>>(h, c3_W1, y);
    gin_layer<1><<<GIN_BLOCKS, 256, 0, stream>>>(y, row_ptr, col_idx, c3_b1,
                                                 Wp + 2 * 2048, c3_b2, nullptr, hbuf);

    // pool + head
    pool_kernel<<<POOL_BLOCKS, 256, 0, stream>>>(hbuf, batch, pool, counts, N_NODES);
    head_kernel<<<N_GRAPHS, 64, 0, stream>>>(pool, counts, fc1_W, fc1_b, predW, predb, out);
}

// Round 11
// 296.862 us; speedup vs baseline: 1.0600x; 1.0208x over previous
//
#include <hip/hip_runtime.h>
#include <hip/hip_fp16.h>
#include <math.h>

#define N_NODES 100000
#define N_EDGES 1600000
#define N_GRAPHS 64
#define EMB 128
#define HID 64

#define BUCKET_BITS 9
#define BUCKET_SZ   512
#define NB          196   // ceil(N_NODES / 512)
#define EPB         4096  // edges per block in bucket passes
#define P12_BLOCKS  391   // ceil(N_EDGES / 4096)
#define NPB         32    // nodes per gin block (8 per wave)

// ---------------- fp16 packed helpers ----------------

typedef _Float16 half2_t __attribute__((ext_vector_type(2)));

__device__ inline unsigned hadd2u(unsigned a, unsigned b) {
    __half2 ha = __builtin_bit_cast(__half2, a);
    __half2 hb = __builtin_bit_cast(__half2, b);
    return __builtin_bit_cast(unsigned, __hadd2(ha, hb));
}

__device__ inline unsigned relu2(unsigned v) {
    unsigned m = (v >> 15) & 0x00010001u;
    return v & ~(m * 0xFFFFu);
}

__device__ inline float fdot2h(unsigned a, unsigned b, float c) {
#if __has_builtin(__builtin_amdgcn_fdot2)
    half2_t ha = __builtin_bit_cast(half2_t, a);
    half2_t hb = __builtin_bit_cast(half2_t, b);
    return __builtin_amdgcn_fdot2(ha, hb, c, false);
#else
    __half2 ha = __builtin_bit_cast(__half2, a);
    __half2 hb = __builtin_bit_cast(__half2, b);
    float2 fa = __half22float2(ha);
    float2 fb = __half22float2(hb);
    return fmaf(fa.x, fb.x, fmaf(fa.y, fb.y, c));
#endif
}

__device__ inline unsigned pack2(float a, float b) {
    __half2 p = __floats2half2_rn(a, b);
    return __builtin_bit_cast(unsigned, p);
}

// ---------------- block-wide exclusive scan over 256 threads ----------------

__device__ inline int block_scan_excl_256(int v) {
    int t = threadIdx.x;
    int lane = t & 63, wid = t >> 6;
    int incl = v;
    #pragma unroll
    for (int off = 1; off < 64; off <<= 1) {
        int u = __shfl_up(incl, off);
        if (lane >= off) incl += u;
    }
    __shared__ int wsum[4];
    if (lane == 63) wsum[wid] = incl;
    __syncthreads();
    int woff = 0;
    for (int w = 0; w < wid; ++w) woff += wsum[w];
    __syncthreads();
    return woff + incl - v;
}

// ---------------- prep: pack 3 weight mats to fp16 + zero accumulators ----------------

__global__ void prep_kernel(const float* __restrict__ w0, const float* __restrict__ w1,
                            const float* __restrict__ w2, unsigned* __restrict__ out,
                            int* __restrict__ bucketCnt, float* __restrict__ pool,
                            float* __restrict__ counts) {
    if (blockIdx.x < 24) {
        int m = blockIdx.x >> 3;
        int i = (blockIdx.x & 7) * 256 + threadIdx.x;
        const float* W = (m == 0) ? w0 : (m == 1) ? w1 : w2;
        int k2 = i >> 6, o = i & 63;
        out[m * 2048 + i] = pack2(W[(2 * k2) * 64 + o], W[(2 * k2 + 1) * 64 + o]);
    } else {
        for (int i = threadIdx.x; i < NB; i += 256) bucketCnt[i] = 0;
        for (int i = threadIdx.x; i < N_GRAPHS * 64; i += 256) pool[i] = 0.0f;
        for (int i = threadIdx.x; i < N_GRAPHS; i += 256) counts[i] = 0.0f;
    }
}

// ---------------- CSR build via bucket semi-sort (uint32-packed entries) ----------------
// entry = (dstLocal9 << 17) | src17

__global__ __launch_bounds__(256) void bucket_count(const int* __restrict__ dst,
                                                    int* __restrict__ bucketCnt,
                                                    int* __restrict__ blockBins, int e) {
    __shared__ int bins[NB];
    for (int i = threadIdx.x; i < NB; i += 256) bins[i] = 0;
    __syncthreads();
    int base = blockIdx.x * EPB;
    #pragma unroll
    for (int j = 0; j < 16; ++j) {
        int i = base + j * 256 + threadIdx.x;
        if (i < e) atomicAdd(&bins[dst[i] >> BUCKET_BITS], 1);
    }
    __syncthreads();
    for (int i = threadIdx.x; i < NB; i += 256) {
        int b = bins[i];
        blockBins[blockIdx.x * NB + i] = b;
        if (b) atomicAdd(&bucketCnt[i], b);
    }
}

__global__ void bucket_scan(const int* __restrict__ bucketCnt, int* __restrict__ bucketOff,
                            int* __restrict__ bucketCur, int* __restrict__ row_ptr) {
    int t = threadIdx.x;
    int v = (t < NB) ? bucketCnt[t] : 0;
    int excl = block_scan_excl_256(v);
    if (t < NB) { bucketOff[t] = excl; bucketCur[t] = excl; }
    if (t == 0) { bucketOff[NB] = N_EDGES; row_ptr[N_NODES] = N_EDGES; }
}

__global__ __launch_bounds__(256) void bucket_scatter(const int* __restrict__ src,
                                                      const int* __restrict__ dst,
                                                      const int* __restrict__ blockBins,
                                                      int* __restrict__ bucketCur,
                                                      unsigned* __restrict__ sorted, int e) {
    __shared__ int lbase[NB];
    __shared__ int gbase[NB];
    __shared__ int cur[NB];
    __shared__ unsigned stage[EPB];        // 16 KB
    __shared__ unsigned char stageb[EPB];  // 4 KB

    int t = threadIdx.x;
    int v = (t < NB) ? blockBins[blockIdx.x * NB + t] : 0;
    int excl = block_scan_excl_256(v);
    if (t < NB) {
        lbase[t] = excl;
        cur[t]   = excl;
        gbase[t] = v ? atomicAdd(&bucketCur[t], v) : 0;
    }
    __syncthreads();

    int base = blockIdx.x * EPB;
    #pragma unroll
    for (int j = 0; j < 16; ++j) {
        int i = base + j * 256 + threadIdx.x;
        if (i < e) {
            int d = dst[i], s = src[i];
            int b = d >> BUCKET_BITS;
            int p = atomicAdd(&cur[b], 1);
            stage[p]  = ((unsigned)(d & (BUCKET_SZ - 1)) << 17) | (unsigned)s;
            stageb[p] = (unsigned char)b;
        }
    }
    __syncthreads();

    int cnt = min(EPB, e - base);
    for (int idx = threadIdx.x; idx < cnt; idx += 256) {
        int b = stageb[idx];
        sorted[gbase[b] + (idx - lbase[b])] = stage[idx];   // contiguous runs per bucket
    }
}

__global__ __launch_bounds__(256) void bucket_csr(const unsigned* __restrict__ sorted,
                                                  const int* __restrict__ bucketOff,
                                                  int* __restrict__ row_ptr,
                                                  int* __restrict__ col_idx) {
    int b  = blockIdx.x;
    int S  = bucketOff[b];
    int Eb = bucketOff[b + 1];
    int n0 = b << BUCKET_BITS;
    int nNodes = min(BUCKET_SZ, N_NODES - n0);

    __shared__ int cnt[BUCKET_SZ];
    __shared__ int excl[BUCKET_SZ];
    __shared__ int cur[BUCKET_SZ];

    for (int i = threadIdx.x; i < BUCKET_SZ; i += 256) cnt[i] = 0;
    __syncthreads();

    for (int idx = S + threadIdx.x; idx < Eb; idx += 256)
        atomicAdd(&cnt[sorted[idx] >> 17], 1);
    __syncthreads();

    int t = threadIdx.x;
    int v = cnt[2 * t] + cnt[2 * t + 1];
    int pe = block_scan_excl_256(v);
    excl[2 * t]     = pe;
    excl[2 * t + 1] = pe + cnt[2 * t];
    __syncthreads();

    for (int i = threadIdx.x; i < nNodes; i += 256)
        row_ptr[n0 + i] = S + excl[i];
    for (int i = threadIdx.x; i < BUCKET_SZ; i += 256) cur[i] = excl[i];
    __syncthreads();

    for (int idx = S + threadIdx.x; idx < Eb; idx += 256) {
        unsigned ed = sorted[idx];
        int ln = (int)(ed >> 17);
        int slot = S + atomicAdd(&cur[ln], 1);
        col_idx[slot] = (int)(ed & 0x1FFFFu);
    }
}

// ---------------- dense projection: y = h @ W (Din -> 64), fp16 out ----------------

template <int DIN>
__global__ __launch_bounds__(256) void project_kernel(const float* __restrict__ h,
                                                      const float* __restrict__ W,
                                                      ushort* __restrict__ y) {
    int wid  = threadIdx.x >> 6;
    int lane = threadIdx.x & 63;
    int node = blockIdx.x * 64 + lane;
    bool valid = node < N_NODES;
    const float4* row = reinterpret_cast<const float4*>(h + (size_t)(valid ? node : 0) * DIN);
    int ob = __builtin_amdgcn_readfirstlane(wid * 16);

    float acc[16];
    #pragma unroll
    for (int o = 0; o < 16; ++o) acc[o] = 0.0f;

    #pragma unroll 4
    for (int k4 = 0; k4 < DIN / 4; ++k4) {
        float4 a = row[k4];
        #pragma unroll
        for (int kk = 0; kk < 4; ++kk) {
            int k = k4 * 4 + kk;
            float av = (kk == 0) ? a.x : (kk == 1) ? a.y : (kk == 2) ? a.z : a.w;
            const float* wr = W + k * 64 + ob;   // uniform address -> s_load
            #pragma unroll
            for (int o = 0; o < 16; ++o)
                acc[o] = fmaf(av, wr[o], acc[o]);
        }
    }

    if (valid) {
        uint4 p0, p1;
        p0.x = pack2(acc[0], acc[1]);   p0.y = pack2(acc[2], acc[3]);
        p0.z = pack2(acc[4], acc[5]);   p0.w = pack2(acc[6], acc[7]);
        p1.x = pack2(acc[8], acc[9]);   p1.y = pack2(acc[10], acc[11]);
        p1.z = pack2(acc[12], acc[13]); p1.w = pack2(acc[14], acc[15]);
        uint4* yr = reinterpret_cast<uint4*>(y + (size_t)node * 64 + ob);
        yr[0] = p0;
        yr[1] = p1;
    }
}

// ---------------- fused layer (round-7 inner loop, proven; 8 nodes/wave) ----------------
// lane = (e4 = lane>>4, c16 = lane&15). 16 lanes x uint2 (8B, 4 halves) = one
// 128B fp16 row per group; 4 rows per load instruction, 16 rows in flight.
// 36 VGPR -> 8 waves/SIMD: TLP does the latency hiding (reg pipelining regressed
// twice: R8 fusion, R9 A/B buffers). DO NOT add register pipelines here.
// MODE 0: h = relu(out) fp32.  MODE 1: h = out fp16 (for pooling).

template <int MODE>
__global__ __launch_bounds__(256) void gin_layer(const ushort* __restrict__ y,
                                                 const int* __restrict__ row_ptr,
                                                 const int* __restrict__ col_idx,
                                                 const float* __restrict__ b1,
                                                 const unsigned* __restrict__ W2p,
                                                 const float* __restrict__ b2,
                                                 float* __restrict__ hout,
                                                 ushort* __restrict__ hout16) {
    __shared__ unsigned sW2p[32 * 64];   // packed half2 [k2][o], 8 KB
    __shared__ unsigned stp[4][32];      // packed st per wave

    {
        const uint4* a = reinterpret_cast<const uint4*>(W2p);
        uint4* dd = reinterpret_cast<uint4*>(sW2p);
        dd[threadIdx.x]       = a[threadIdx.x];
        dd[threadIdx.x + 256] = a[threadIdx.x + 256];
    }
    __syncthreads();

    int wid  = threadIdx.x >> 6;
    int lane = threadIdx.x & 63;
    int e4   = lane >> 4;       // edge sub-group 0..3
    int c16  = lane & 15;       // channel chunk (4 halves) 0..15

    const uint2* yp = reinterpret_cast<const uint2*>(y);  // row stride = 16 uint2
    float4 b1f = reinterpret_cast<const float4*>(b1)[c16];
    unsigned bp0 = pack2(b1f.x, b1f.y);
    unsigned bp1 = pack2(b1f.z, b1f.w);
    float b2v = b2[lane];

    #pragma unroll 1
    for (int t = 0; t < 8; ++t) {
        int node = blockIdx.x * NPB + wid * 8 + t;

        int start = row_ptr[node];
        int end   = row_ptr[node + 1];

        unsigned a0 = 0u, a1 = 0u;
        if (e4 == 0) {
            uint2 s = yp[(size_t)node * 16 + c16];   // self term
            a0 = s.x; a1 = s.y;
        }

        int base = start;
        // main: 16 edges per iteration, 4 row-loads in flight per lane-group
        for (; base + 16 <= end; base += 16) {
            int i0 = col_idx[base + e4];
            int i1 = col_idx[base + 4 + e4];
            int i2 = col_idx[base + 8 + e4];
            int i3 = col_idx[base + 12 + e4];
            uint2 u0 = yp[(size_t)i0 * 16 + c16];
            uint2 u1 = yp[(size_t)i1 * 16 + c16];
            uint2 u2 = yp[(size_t)i2 * 16 + c16];
            uint2 u3 = yp[(size_t)i3 * 16 + c16];
            a0 = hadd2u(a0, u0.x); a1 = hadd2u(a1, u0.y);
            a0 = hadd2u(a0, u1.x); a1 = hadd2u(a1, u1.y);
            a0 = hadd2u(a0, u2.x); a1 = hadd2u(a1, u2.y);
            a0 = hadd2u(a0, u3.x); a1 = hadd2u(a1, u3.y);
        }
        // tail: rem < 16, straight-line predicated (loads stay in flight)
        {
            uint2 z = make_uint2(0u, 0u);
            uint2 u0 = z, u1 = z, u2 = z, u3 = z;
            if (base + e4 < end)      u0 = yp[(size_t)col_idx[base + e4] * 16 + c16];
            if (base + 4 + e4 < end)  u1 = yp[(size_t)col_idx[base + 4 + e4] * 16 + c16];
            if (base + 8 + e4 < end)  u2 = yp[(size_t)col_idx[base + 8 + e4] * 16 + c16];
            if (base + 12 + e4 < end) u3 = yp[(size_t)col_idx[base + 12 + e4] * 16 + c16];
            a0 = hadd2u(a0, u0.x); a1 = hadd2u(a1, u0.y);
            a0 = hadd2u(a0, u1.x); a1 = hadd2u(a1, u1.y);
            a0 = hadd2u(a0, u2.x); a1 = hadd2u(a1, u2.y);
            a0 = hadd2u(a0, u3.x); a1 = hadd2u(a1, u3.y);
        }

        // reduce across the 4 edge groups (lanes differing in bits 4,5)
        #pragma unroll
        for (int m = 16; m <= 32; m <<= 1) {
            a0 = hadd2u(a0, (unsigned)__shfl_xor((int)a0, m));
            a1 = hadd2u(a1, (unsigned)__shfl_xor((int)a1, m));
        }

        // bias + relu in packed fp16; publish to wave-private st
        a0 = relu2(hadd2u(a0, bp0));
        a1 = relu2(hadd2u(a1, bp1));
        if (e4 == 0)
            reinterpret_cast<uint2*>(stp[wid])[c16] = make_uint2(a0, a1);

        // GEMM2: u[lane] = b2[lane] + sum_k2 dot2(st2[k2], W2p[k2][lane])
        float u = b2v;
        const uint4* sp = reinterpret_cast<const uint4*>(stp[wid]);
        #pragma unroll
        for (int j = 0; j < 8; ++j) {
            uint4 q = sp[j];
            u = fdot2h(q.x, sW2p[(4 * j + 0) * 64 + lane], u);
            u = fdot2h(q.y, sW2p[(4 * j + 1) * 64 + lane], u);
            u = fdot2h(q.z, sW2p[(4 * j + 2) * 64 + lane], u);
            u = fdot2h(q.w, sW2p[(4 * j + 3) * 64 + lane], u);
        }
        if (MODE == 0) {
            hout[(size_t)node * 64 + lane] = fmaxf(u, 0.0f);
        } else {
            hout16[(size_t)node * 64 + lane] = __half_as_ushort(__float2half_rn(u));
        }
    }
}

// ---------------- pooling: segment mean over fp16 h (batch is sorted) ----------------

__global__ __launch_bounds__(256) void pool_kernel(const ushort* __restrict__ h,
                                                   const int* __restrict__ batch,
                                                   float* __restrict__ pool,
                                                   float* __restrict__ counts, int n) {
    int gwave = (blockIdx.x * 256 + threadIdx.x) >> 6;
    int lane  = threadIdx.x & 63;
    int s = gwave * 64;
    if (s >= n) return;
    int nhere = min(64, n - s);

    int bv = (s + lane < n) ? batch[s + lane] : -1;
    int cur = __shfl(bv, 0);
    float acc = 0.0f, cnt = 0.0f;

    #pragma unroll 1
    for (int i0 = 0; i0 < 64; i0 += 8) {
        float v[8];
        #pragma unroll
        for (int j = 0; j < 8; ++j) {
            int i = i0 + j;
            v[j] = (i < nhere)
                 ? __half2float(__ushort_as_half(h[(size_t)(s + i) * 64 + lane]))
                 : 0.0f;
        }
        #pragma unroll
        for (int j = 0; j < 8; ++j) {
            int i = i0 + j;
            if (i < nhere) {
                int g = __shfl(bv, i);
                if (g != cur) {   // wave-uniform, rare
                    atomicAdd(&pool[cur * 64 + lane], acc);
                    if (lane == 0) atomicAdd(&counts[cur], cnt);
                    cur = g; acc = 0.0f; cnt = 0.0f;
                }
                acc += v[j];
                cnt += 1.0f;
            }
        }
    }
    atomicAdd(&pool[cur * 64 + lane], acc);
    if (lane == 0) atomicAdd(&counts[cur], cnt);
}

// ---------------- head: pooled @ fc1 + b, @ pred + b, sigmoid ----------------

__global__ void head_kernel(const float* __restrict__ pool, const float* __restrict__ counts,
                            const float* __restrict__ fc1_W, const float* __restrict__ fc1_b,
                            const float* __restrict__ pred_W, const float* __restrict__ pred_b,
                            float* __restrict__ out) {
    int g = blockIdx.x;
    int t = threadIdx.x;
    float s = 0.0f;
    if (t < 32) {
        float cnt = fmaxf(counts[g], 1.0f);
        float inv = 1.0f / cnt;
        float f = fc1_b[t];
        #pragma unroll
        for (int k = 0; k < 64; ++k)
            f = fmaf(pool[g * 64 + k] * inv, fc1_W[k * 32 + t], f);
        s = f * pred_W[t];
    }
    #pragma unroll
    for (int off = 32; off > 0; off >>= 1) s += __shfl_down(s, off);
    if (t == 0) out[g] = 1.0f / (1.0f + expf(-(s + pred_b[0])));
}

// ---------------- launch ----------------

extern "C" void kernel_launch(void* const* d_in, const int* in_sizes, int n_in,
                              void* d_out, int out_size, void* d_ws, size_t ws_size,
                              hipStream_t stream) {
    const float* x      = (const float*)d_in[0];
    const int*   e_src  = (const int*)d_in[1];
    const int*   e_dst  = ((const int*)d_in[1]) + N_EDGES;
    const int*   batch  = (const int*)d_in[2];
    const float* c1_W1 = (const float*)d_in[3];
    const float* c1_b1 = (const float*)d_in[4];
    const float* c1_W2 = (const float*)d_in[5];
    const float* c1_b2 = (const float*)d_in[6];
    const float* c2_W1 = (const float*)d_in[7];
    const float* c2_b1 = (const float*)d_in[8];
    const float* c2_W2 = (const float*)d_in[9];
    const float* c2_b2 = (const float*)d_in[10];
    const float* c3_W1 = (const float*)d_in[11];
    const float* c3_b1 = (const float*)d_in[12];
    const float* c3_W2 = (const float*)d_in[13];
    const float* c3_b2 = (const float*)d_in[14];
    const float* fc1_W = (const float*)d_in[15];
    const float* fc1_b = (const float*)d_in[16];
    const float* predW = (const float*)d_in[17];
    const float* predb = (const float*)d_in[18];
    float* out = (float*)d_out;

    char* ws = (char*)d_ws;
    size_t off = 0;
    auto carve = [&](size_t bytes) {
        char* p = ws + off;
        off += (bytes + 255) & ~(size_t)255;
        return p;
    };
    ushort* y        = (ushort*)carve((size_t)N_NODES * 64 * 2);  // 12.8 MB
    float*  h        = (float*)carve((size_t)N_NODES * 64 * 4);   // 25.6 MB
    int*    row_ptr  = (int*)carve(((size_t)N_NODES + 1) * 4);
    int*    col_idx  = (int*)carve((size_t)N_EDGES * 4);
    int*    bucketCnt = (int*)carve(NB * 4);
    int*    bucketOff = (int*)carve((NB + 1) * 4);
    int*    bucketCur = (int*)carve(NB * 4);
    int*    blockBins = (int*)carve((size_t)P12_BLOCKS * NB * 4); // 306 KB
    float*  pool     = (float*)carve(N_GRAPHS * 64 * 4);
    float*  counts   = (float*)carve(N_GRAPHS * 4);
    unsigned* Wp     = (unsigned*)carve(3 * 2048 * 4);
    unsigned* sorted = (unsigned*)y;        // 6.4 MB, dead before proj1 writes y
    ushort* hbuf     = (ushort*)h;          // layer-3 fp16 out, h dead by then
    (void)ws_size; (void)n_in; (void)in_sizes; (void)out_size;

    const int GIN_BLOCKS  = N_NODES / NPB;             // 3125 (32 nodes/block)
    const int PROJ_BLOCKS = (N_NODES + 63) / 64;       // 1563
    const int POOL_BLOCKS = (N_NODES + 255) / 256;     // 391

    // prep: weight pack + zero accumulators (replaces wpack3 + 2 memsets)
    prep_kernel<<<25, 256, 0, stream>>>(c1_W2, c2_W2, c3_W2, Wp, bucketCnt, pool, counts);

    // CSR build via bucket semi-sort
    bucket_count<<<P12_BLOCKS, 256, 0, stream>>>(e_dst, bucketCnt, blockBins, N_EDGES);
    bucket_scan<<<1, 256, 0, stream>>>(bucketCnt, bucketOff, bucketCur, row_ptr);
    bucket_scatter<<<P12_BLOCKS, 256, 0, stream>>>(e_src, e_dst, blockBins, bucketCur,
                                                   sorted, N_EDGES);
    bucket_csr<<<NB, 256, 0, stream>>>(sorted, bucketOff, row_ptr, col_idx);

    // layer 1 (project 128->64 BEFORE aggregation: linearity of W1)
    project_kernel<EMB><<<PROJ_BLOCKS, 256, 0, stream>>>(x, c1_W1, y);
    gin_layer<0><<<GIN_BLOCKS, 256, 0, stream>>>(y, row_ptr, col_idx, c1_b1,
                                                 Wp + 0 * 2048, c1_b2, h, nullptr);
    // layer 2
    project_kernel<HID><<<PROJ_BLOCKS, 256, 0, stream>>>(h, c2_W1, y);
    gin_layer<0><<<GIN_BLOCKS, 256, 0, stream>>>(y, row_ptr, col_idx, c2_b1,
                                                 Wp + 1 * 2048, c2_b2, h, nullptr);
    // layer 3 (no output relu, fp16 out for pooling)
    project_kernel<HID><<<PROJ_BLOCKS, 256, 0, stream>>>(h, c3_W1, y);
    gin_layer<1><<<GIN_BLOCKS, 256, 0, stream>>>(y, row_ptr, col_idx, c3_b1,
                                                 Wp + 2 * 2048, c3_b2, nullptr, hbuf);

    // pool + head
    pool_kernel<<<POOL_BLOCKS, 256, 0, stream>>>(hbuf, batch, pool, counts, N_NODES);
    head_kernel<<<N_GRAPHS, 64, 0, stream>>>(pool, counts, fc1_W, fc1_b, predW, predb, out);
}